// Round 14
// baseline (146.487 us; speedup 1.0000x reference)
//
#include <hip/hip_runtime.h>
#include <stdint.h>
#include <stddef.h>

typedef __attribute__((ext_vector_type(8)))  short bf16x8;
typedef __attribute__((ext_vector_type(2)))  float f32x2;
typedef __attribute__((ext_vector_type(4)))  float f32x4;
typedef __attribute__((ext_vector_type(16))) float f32x16;
typedef __attribute__((ext_vector_type(4)))  float float4v;
typedef __attribute__((ext_vector_type(4)))  int   int4v;

#define DEV static __device__ __forceinline__

static constexpr int EMBED  = 1024;
static constexpr int HEADS  = 16;
static constexpr int SEQ    = 2048;

// fp32 -> bf16 bits, round-to-nearest-even
DEV short f2bf(float f) {
  union { float f; unsigned u; } x; x.f = f;
  unsigned r = x.u + 0x7fffu + ((x.u >> 16) & 1u);
  return (short)(r >> 16);
}

// v_cvt_pk_bf16_f32 PROVEN exactly RNE on gfx950 (r10 vs r11 bit-identical).
DEV int cvtpk(float a, float b) {   // low word = bf16(a), high word = bf16(b)
  int r; asm("v_cvt_pk_bf16_f32 %0, %1, %2" : "=v"(r) : "v"(a), "v"(b)); return r;
}

DEV float fexp2(float x) { float r; asm("v_exp_f32 %0, %1" : "=v"(r) : "v"(x)); return r; }

#define MFMA16(a,b,c) __builtin_amdgcn_mfma_f32_16x16x32_bf16((a),(b),(c),0,0,0)
#define MFMA32(a,b,c) __builtin_amdgcn_mfma_f32_32x32x16_bf16((a),(b),(c),0,0,0)
// NOTE: imm-offset arg of global_load_lds applies to the LDS destination
// (round-7 failure). Always pass 0 and do explicit pointer arithmetic.
#define GLDS(g,l) __builtin_amdgcn_global_load_lds( \
    (const __attribute__((address_space(1))) void*)(g), \
    (__attribute__((address_space(3))) void*)(l), 16, 0, 0)
#define SBAR0() __builtin_amdgcn_sched_barrier(0)
#define ZERO16 {0,0,0,0,0,0,0,0,0,0,0,0,0,0,0,0}
#define ROT3(x) ((x) == 2 ? 0 : (x) + 1)

// NUMERICS RULE (r10/r11): reference quantizes Q on the UNSCALED bf16 grid.
// Round Q unscaled; apply log2(e)/32 in fp32 inside attention.
//
// SYNC TEMPLATE (this round): triple-buffer LDS ring, ONE barrier/iter.
// Iter t: vmcnt(4) [drains G(t)+M(t)]; barrier; issue M(t+1), G(t+2) into
// buf[(t+2)%3]; compute from buf[t%3]; SBAR0 (no ds_read may sink past the
// next barrier — G(t+3) would overwrite buf[t%3]). WAR-safety: G(t+2) targets
// buf[(t-1)%3], whose readers finished before this iter's barrier.

// ---------------------------------------------------------------- convert
struct CvtArgs { const float* src[7]; short* dst[7]; int n[7]; };

__global__ void cvt_bf16(CvtArgs a) {
  const int task = blockIdx.y;
  const int i = (blockIdx.x * 256 + threadIdx.x) * 8;
  if (i >= a.n[task]) return;
  const float4v* s = (const float4v*)(a.src[task] + i);
  float4v x = s[0], y = s[1];
  bf16x8 o;
  o[0] = f2bf(x[0]); o[1] = f2bf(x[1]); o[2] = f2bf(x[2]); o[3] = f2bf(x[3]);
  o[4] = f2bf(y[0]); o[5] = f2bf(y[1]); o[6] = f2bf(y[2]); o[7] = f2bf(y[3]);
  *(bf16x8*)(a.dst[task] + i) = o;
}

// ---------------------------------------------------------------- mask bitpack
__global__ void maskpack(const int* __restrict__ m, unsigned long long* __restrict__ out) {
  const int gw = (blockIdx.x * 256 + threadIdx.x) >> 6;
  const int l  = threadIdx.x & 63;
  const int n = gw >> 16, kvblk = (gw >> 11) & 31, q = gw & 2047;
  int v = m[((size_t)n * SEQ + q) * SEQ + kvblk * 64 + l];
  unsigned long long b = __ballot(v != 0);
  if (l == 0) out[((size_t)n * 32 + kvblk) * SEQ + q] = b;
}

// ---------------------------------------------------------------- GEMM core (C = A @ B^T, K=1024)
// Triple-buffer ring, 1 barrier/iter (see SYNC TEMPLATE above).
// MODE 0: Q  -> bf16 per-head [n][h][s][d]   (UNSCALED)
// MODE 2: K  -> bf16 per-head [n][h][s][d ^ ((s&7)<<3)]
// MODE 3: V  -> bf16 per-head transposed tiled [n][h][s>>6][d][(s&63) ^ ((d&7)<<3)]
// MODE 1: out-> f32 + bias, row-major [M][EMBED]
template<int MODE>
DEV void gemm_core(const int vv, const short* __restrict__ A, const short* __restrict__ B,
                   short* __restrict__ Cb, float* __restrict__ Cf,
                   const float* __restrict__ bias, short* As, short* Bs)
{
  const int t = threadIdx.x;
  const int l = t & 63, w = t >> 6;
  const int lr = l & 15, lh = l >> 4;
  const int m0 = (vv >> 3) * 128, n0 = (vv & 7) * 128;
  const int wr = w >> 1, wc = w & 1;
  f32x4 acc[4][4] = {};

  const int rA = t >> 2, cA = (t & 3) * 8;
  const short* gA  = A + (size_t)(m0 + rA) * 1024 + cA;
  const short* gA2 = gA + (size_t)64 * 1024;
  const short* gB  = B + (size_t)(n0 + rA) * 1024 + cA;
  const short* gB2 = gB + (size_t)64 * 1024;

  // prologue: stage tiles 0 and 1 into bufs 0,1 (order pinned)
  GLDS(gA,       As + w * 512);
  GLDS(gA2,      As + 2048 + w * 512);
  GLDS(gB,       Bs + w * 512);
  GLDS(gB2,      Bs + 2048 + w * 512);
  SBAR0();
  GLDS(gA + 32,  As + 4096 + w * 512);
  GLDS(gA2 + 32, As + 4096 + 2048 + w * 512);
  GLDS(gB + 32,  Bs + 4096 + w * 512);
  GLDS(gB2 + 32, Bs + 4096 + 2048 + w * 512);
  SBAR0();

  int cb = 0, sb = 2;   // compute buf = it%3, stage buf = (it+2)%3
  #pragma unroll 1
  for (int it = 0; it < 32; ++it) {
    if (it < 31) { asm volatile("s_waitcnt vmcnt(4)" ::: "memory"); }
    else         { asm volatile("s_waitcnt vmcnt(0)" ::: "memory"); }
    SBAR0();
    __builtin_amdgcn_s_barrier();
    SBAR0();
    if (it < 30) {
      const int kt = (it + 2) * 32;
      GLDS(gA + kt,  As + sb * 4096 + w * 512);
      GLDS(gA2 + kt, As + sb * 4096 + 2048 + w * 512);
      GLDS(gB + kt,  Bs + sb * 4096 + w * 512);
      GLDS(gB2 + kt, Bs + sb * 4096 + 2048 + w * 512);
      SBAR0();
    }

    const short* as = As + cb * 4096;
    const short* bs = Bs + cb * 4096;
    bf16x8 af[4], bq[4];
    #pragma unroll
    for (int i = 0; i < 4; ++i)
      af[i] = *(const bf16x8*)&as[(wr * 64 + i * 16 + lr) * 32 + lh * 8];
    #pragma unroll
    for (int i = 0; i < 4; ++i)
      bq[i] = *(const bf16x8*)&bs[(wc * 64 + i * 16 + lr) * 32 + lh * 8];
    #pragma unroll
    for (int mi = 0; mi < 4; ++mi)
      #pragma unroll
      for (int ni = 0; ni < 4; ++ni)
        acc[mi][ni] = MFMA16(af[mi], bq[ni], acc[mi][ni]);

    SBAR0();   // REQUIRED: no ds_read sinks past the next barrier (G(t+3) WAR)
    cb = ROT3(cb); sb = ROT3(sb);
  }

  #pragma unroll
  for (int mi = 0; mi < 4; ++mi)
    #pragma unroll
    for (int ni = 0; ni < 4; ++ni)
      #pragma unroll
      for (int r = 0; r < 4; ++r) {
        const int m = m0 + wr * 64 + mi * 16 + lh * 4 + r;
        const int e = n0 + wc * 64 + ni * 16 + lr;
        const float v = acc[mi][ni][r];
        const int nb = m >> 11, s = m & 2047, hh = e >> 6, d = e & 63;
        if (MODE == 0) {
          Cb[(((size_t)(nb * HEADS + hh)) * SEQ + s) * 64 + d] = f2bf(v);
        } else if (MODE == 2) {
          Cb[(((size_t)(nb * HEADS + hh)) * SEQ + s) * 64 + (d ^ ((s & 7) << 3))] = f2bf(v);
        } else if (MODE == 3) {
          Cb[(((size_t)(nb * HEADS + hh)) * 32 + (s >> 6)) * 4096 + d * 64 +
             ((s & 63) ^ ((d & 7) << 3))] = f2bf(v);
        } else {
          Cf[(size_t)m * EMBED + e] = v + bias[e];
        }
      }
}

// Q/K/V projections fused: grid 768, slice = lin>>8, per-slice XCD swizzle.
__global__ __launch_bounds__(256, 2)
void gemm_qkv(const short* __restrict__ Ab, const short* __restrict__ Bb,
              short* __restrict__ Qp, short* __restrict__ Kp, short* __restrict__ VTp)
{
  __shared__ short As[3][4096];
  __shared__ short Bs[3][4096];
  const int lin = blockIdx.x;
  const int s = lin >> 8, j = lin & 255;
  const int vv = (j & 7) * 32 + (j >> 3);
  const short* A = Ab + (size_t)s * 4194304;   // qb/kb/vb stride 8 MiB
  const short* B = Bb + (size_t)s * 1048576;   // wqb/wkb/wvb stride 2 MiB
  if (s == 0)      gemm_core<0>(vv, A, B, Qp,  nullptr, nullptr, &As[0][0], &Bs[0][0]);
  else if (s == 1) gemm_core<2>(vv, A, B, Kp,  nullptr, nullptr, &As[0][0], &Bs[0][0]);
  else             gemm_core<3>(vv, A, B, VTp, nullptr, nullptr, &As[0][0], &Bs[0][0]);
}

__global__ __launch_bounds__(256, 2)
void gemm_out(const short* __restrict__ A, const short* __restrict__ B,
              float* __restrict__ Cf, const float* __restrict__ bias)
{
  __shared__ short As[3][4096];
  __shared__ short Bs[3][4096];
  const int lin = blockIdx.x;
  const int vv = (lin & 7) * 32 + (lin >> 3);
  gemm_core<1>(vv, A, B, nullptr, Cf, bias, &As[0][0], &Bs[0][0]);
}

// ---------------------------------------------------------------- attention
// r13-proven math (bit-identical); sync restructured to the triple-buffer
// 1-barrier/iter template (see top). Queue at iter-t top:
// [G(t)x4, M(t), G(t+1)x4] -> vmcnt(4) drains G(t)+M(t).
__global__ __launch_bounds__(256, 2)
void attn256(const short* __restrict__ Qp, const short* __restrict__ Kp,
             const short* __restrict__ VTp, const unsigned long long* __restrict__ MbT,
             short* __restrict__ Aout)
{
  __shared__ short lds[3][8192];   // ring: per buf K tile 4096 | VT tile 4096

  const int t = threadIdx.x, l = t & 63, w = t >> 6;   // w: 0..3
  const int lq = l & 31, hi = l >> 5;
  const int lin = blockIdx.x;
  const int vv = (lin & 7) * 64 + (lin >> 3);   // [0,512)
  const int hl = vv >> 4, qb = vv & 15;
  const int n = hl >> 4, h = hl & 15;
  const int q0 = qb * 128;
  const int myq = q0 + w * 32 + lq;
  const size_t hb = (size_t)(n * HEADS + h) * SEQ * 64;
  const short* Qh = Qp + hb;
  const unsigned long long* Mh = MbT + (size_t)n * (32 * SEQ);
  const float SCL = 0.045084220027780106f;   // log2(e)/32 — fp32, applied here

  // Q fragments (B-operand), resident all block
  bf16x8 qf[4];
  #pragma unroll
  for (int ks = 0; ks < 4; ++ks)
    qf[ks] = *(const bf16x8*)(Qh + (size_t)myq * 64 + ks * 16 + hi * 8);

  const short ONE = (short)0x3F80;
  const bf16x8 onesv = {ONE, ONE, ONE, ONE, ONE, ONE, ONE, ONE};
  const f32x16 zerov = ZERO16;

  f32x16 acco[2] = { ZERO16, ZERO16 };
  f32x16 accl = ZERO16;   // denominator accumulator (all regs = q-row sum)

  const short* kgp = Kp + hb + w * 1024 + l * 8;
  const short* vgp = VTp + hb + w * 1024 + l * 8;
  const unsigned long long* mp = MbT + (size_t)n * (32 * SEQ) + myq;

  // prologue: M(0) load, then tiles 0,1 into bufs 0,1 (order pinned)
  unsigned long long mw = *mp; mp += SEQ;
  SBAR0();
  GLDS(kgp,        &lds[0][w * 1024]);
  GLDS(kgp + 512,  &lds[0][w * 1024 + 512]);
  GLDS(vgp,        &lds[0][4096 + w * 1024]);
  GLDS(vgp + 512,  &lds[0][4096 + w * 1024 + 512]);
  SBAR0();
  GLDS(kgp + 4096, &lds[1][w * 1024]);
  GLDS(kgp + 4608, &lds[1][w * 1024 + 512]);
  GLDS(vgp + 4096, &lds[1][4096 + w * 1024]);
  GLDS(vgp + 4608, &lds[1][4096 + w * 1024 + 512]);
  SBAR0();
  kgp += 8192; vgp += 8192;   // -> tile 2

  int cb = 0, sb = 2;   // compute buf = tt%3, stage buf = (tt+2)%3
  #pragma unroll 1
  for (int tt = 0; tt < 32; ++tt) {
    if (tt < 31) { asm volatile("s_waitcnt vmcnt(4)" ::: "memory"); }
    else         { asm volatile("s_waitcnt vmcnt(0)" ::: "memory"); }
    SBAR0();
    __builtin_amdgcn_s_barrier();
    SBAR0();

    unsigned long long mw_next = 0;
    if (tt < 31) {
      mw_next = *mp; mp += SEQ;
      SBAR0();   // pin: M(t+1) precedes the GLDS quad in the vmem queue
    }
    if (tt < 30) {
      GLDS(kgp,       &lds[sb][w * 1024]);
      GLDS(kgp + 512, &lds[sb][w * 1024 + 512]);
      GLDS(vgp,       &lds[sb][4096 + w * 1024]);
      GLDS(vgp + 512, &lds[sb][4096 + w * 1024 + 512]);
      kgp += 4096; vgp += 4096;
      SBAR0();
    }

    const short* Ks  = &lds[cb][0];
    const short* VTs = &lds[cb][4096];

    #pragma unroll
    for (int half = 0; half < 2; ++half) {
      // ---- S^T[32kv][32q] over d=64: A = K rows, B = Q (reg); C0 = zerov
      f32x16 sacc;
      __builtin_amdgcn_s_setprio(1);
      #pragma unroll
      for (int ks = 0; ks < 4; ++ks) {
        const int d = ks * 16 + hi * 8;
        bf16x8 kf = *(const bf16x8*)&Ks[(half * 32 + lq) * 64 + (d ^ ((lq & 7) << 3))];
        sacc = MFMA32(kf, qf[ks], ks == 0 ? zerov : sacc);
      }
      __builtin_amdgcn_s_setprio(0);
      // ---- p = exp2(fma(sacc, SCL, bias)); bias = -200 where masked
      const unsigned mmw = ~(unsigned)(mw >> (half * 32 + hi * 4));
      float p[16];
      #pragma unroll
      for (int r = 0; r < 16; ++r) {
        const int idx = (r & 3) + 8 * (r >> 2);
        union { int i; float f; } b;
        b.i = __builtin_amdgcn_sbfe(mmw, idx, 1) & 0xC3480000;   // 0 or -200.0f
        p[r] = fexp2(__builtin_fmaf(sacc[r], SCL, b.f));
      }
      // ---- P^T B-fragments: 4 cvt_pk + 2 permlane32_swap per 16-kv step
      bf16x8 pf[2];
      #pragma unroll
      for (int kb = 0; kb < 2; ++kb) {
        int x1 = cvtpk(p[kb * 8 + 0], p[kb * 8 + 1]);
        int y1 = cvtpk(p[kb * 8 + 4], p[kb * 8 + 5]);
        int x2 = cvtpk(p[kb * 8 + 2], p[kb * 8 + 3]);
        int y2 = cvtpk(p[kb * 8 + 6], p[kb * 8 + 7]);
        asm("v_permlane32_swap_b32 %0, %1" : "+v"(x1), "+v"(y1));
        asm("v_permlane32_swap_b32 %0, %1" : "+v"(x2), "+v"(y2));
        union { int w4[4]; bf16x8 v; } u;
        u.w4[0] = x1; u.w4[1] = x2; u.w4[2] = y1; u.w4[3] = y2;
        pf[kb] = u.v;
      }
      // ---- O^T += V^T . P^T ; denominator accl += ones . P^T (MFMA pipe)
      __builtin_amdgcn_s_setprio(1);
      accl = MFMA32(onesv, pf[0], accl);
      accl = MFMA32(onesv, pf[1], accl);
      #pragma unroll
      for (int dt = 0; dt < 2; ++dt) {
        const int d = dt * 32 + lq;
        #pragma unroll
        for (int kb = 0; kb < 2; ++kb) {
          const int kv = half * 32 + kb * 16 + hi * 8;
          bf16x8 vf = *(const bf16x8*)&VTs[d * 64 + (kv ^ ((d & 7) << 3))];
          acco[dt] = MFMA32(vf, pf[kb], acco[dt]);
        }
      }
      __builtin_amdgcn_s_setprio(0);
    }
    mw = mw_next;
    SBAR0();   // REQUIRED: no ds_read sinks past the next barrier (G(t+3) WAR)
    cb = ROT3(cb); sb = ROT3(sb);
  }

  // ---- epilogue: scale by 1/rowsum (accl: every reg = q-row sum), store bf16
  // buf0 reuse is safe: all waves passed the iter-31 barrier => iter-30
  // (the last buf0 readers) fully complete.
  const float invs = 1.f / (accl[0] + 1e-30f);

  short* ot = &lds[0][0] + w * 2048;   // wave-private 32q x 64d (swizzled)
  #pragma unroll
  for (int dt = 0; dt < 2; ++dt)
    #pragma unroll
    for (int r = 0; r < 16; ++r) {
      const int d = dt * 32 + (r & 3) + 8 * (r >> 2) + 4 * hi;
      ot[lq * 64 + (d ^ ((lq & 7) << 3))] = f2bf(acco[dt][r] * invs);
    }
  __syncthreads();

  const int qq = l >> 1, hb2 = l & 1;
  #pragma unroll
  for (int it = 0; it < 4; ++it) {
    const int didx = (hb2 * 32 + it * 8) ^ ((qq & 7) << 3);
    bf16x8 v = *(const bf16x8*)&ot[qq * 64 + didx];
    *(bf16x8*)&Aout[((size_t)(n * SEQ + q0 + w * 32 + qq)) * EMBED + h * 64 + hb2 * 32 + it * 8] = v;
  }
}

// ---------------------------------------------------------------- launcher
extern "C" void kernel_launch(void* const* d_in, const int* in_sizes, int n_in,
                              void* d_out, int out_size, void* d_ws, size_t ws_size,
                              hipStream_t stream) {
  (void)in_sizes; (void)n_in; (void)out_size;
  const float* queries = (const float*)d_in[0];
  const float* keys    = (const float*)d_in[1];
  const float* values  = (const float*)d_in[2];
  const int*   mask    = (const int*)d_in[3];
  const float* Wq      = (const float*)d_in[4];
  const float* Wk      = (const float*)d_in[5];
  const float* Wv      = (const float*)d_in[6];
  const float* Wo      = (const float*)d_in[7];
  const float* bo      = (const float*)d_in[8];

  const size_t NEED = (size_t)76 * 1024 * 1024;
  if (ws_size < NEED) return;

  char* ws = (char*)d_ws;
  short* qb   = (short*)(ws + 0);           // qb/kb/vb contiguous, stride 8 MiB
  short* kb   = (short*)(ws + (8u << 20));
  short* vb   = (short*)(ws + (16u << 20));
  short* wqb  = (short*)(ws + (24u << 20)); // wqb/wkb/wvb contiguous, stride 2 MiB
  short* wkb  = (short*)(ws + (26u << 20));
  short* wvb  = (short*)(ws + (28u << 20));
  short* wob  = (short*)(ws + (30u << 20));
  unsigned long long* mbits = (unsigned long long*)(ws + (32u << 20)); // 1 MiB
  short* Qp   = (short*)(ws + (40u << 20));
  short* Kp   = (short*)(ws + (48u << 20));
  short* VTp  = (short*)(ws + (56u << 20));
  short* ao   = (short*)(ws + (64u << 20));

  const int NTOK = 2 * SEQ * EMBED;
  const int NW   = EMBED * EMBED;

  CvtArgs ca;
  ca.src[0] = queries; ca.dst[0] = qb;  ca.n[0] = NTOK;
  ca.src[1] = keys;    ca.dst[1] = kb;  ca.n[1] = NTOK;
  ca.src[2] = values;  ca.dst[2] = vb;  ca.n[2] = NTOK;
  ca.src[3] = Wq;      ca.dst[3] = wqb; ca.n[3] = NW;
  ca.src[4] = Wk;      ca.dst[4] = wkb; ca.n[4] = NW;
  ca.src[5] = Wv;      ca.dst[5] = wvb; ca.n[5] = NW;
  ca.src[6] = Wo;      ca.dst[6] = wob; ca.n[6] = NW;
  cvt_bf16<<<dim3(2048, 7), 256, 0, stream>>>(ca);

  maskpack<<<dim3(32768), 256, 0, stream>>>(mask, mbits);

  gemm_qkv<<<dim3(768), 256, 0, stream>>>(qb, wqb, Qp, Kp, VTp);

  attn256<<<dim3(512), 256, 0, stream>>>(Qp, Kp, VTp, mbits, ao);

  gemm_out<<<dim3(256), 256, 0, stream>>>(ao, wob, (float*)d_out, bo);
}